// Round 17
// baseline (288.376 us; speedup 1.0000x reference)
//
#include <hip/hip_runtime.h>

#define N_NODES 50000
#define N_EDGES 800000
#define NUM_GRAPHS 16
#define NUM_CLASSES 247
#define SCAN_BLOCKS ((N_NODES + 255) / 256)  // 196

typedef __attribute__((ext_vector_type(8))) short bf16x8;
typedef __attribute__((ext_vector_type(4))) float f32x4;

static inline int nblk(long n) { return (int)((n + 255) / 256); }

__device__ __forceinline__ float bfl(unsigned short u) {
    return __uint_as_float((unsigned)u << 16);
}
__device__ __forceinline__ unsigned short bf16_rne(float f) {
    unsigned u = __float_as_uint(f);
    u += 0x7FFF + ((u >> 16) & 1);
    return (unsigned short)(u >> 16);
}

// ---- degree histogram into 8 XCD-local copies; returns rank within copy ----
__global__ void k_deg(const int* __restrict__ col, int* __restrict__ degc,
                      int* __restrict__ pos, int E) {
    int e = blockIdx.x * blockDim.x + threadIdx.x;
    if (e >= E) return;
    int c8 = (e >> 8) & 7;
    pos[e] = atomicAdd(&degc[c8 * N_NODES + col[e]], 1);
}

// ---- scan phase 1: per-block exclusive scan of total degree + batch hist ---
__global__ __launch_bounds__(256) void k_scan1(const int* __restrict__ degc,
                                               int* __restrict__ rowptr,
                                               int* __restrict__ bsum,
                                               const int* __restrict__ batch,
                                               float* __restrict__ pcnt, int N) {
    __shared__ int buf[256];
    __shared__ int hist[NUM_GRAPHS];
    int t = threadIdx.x;
    if (t < NUM_GRAPHS) hist[t] = 0;
    int i = blockIdx.x * 256 + t;
    int v = 0;
    if (i < N) {
#pragma unroll
        for (int c = 0; c < 8; ++c) v += degc[c * N_NODES + i];
        atomicAdd(&hist[batch[i]], 1);
    }
    buf[t] = v;
    __syncthreads();
#pragma unroll
    for (int off = 1; off < 256; off <<= 1) {
        int tmp = (t >= off) ? buf[t - off] : 0;
        __syncthreads();
        if (t >= off) buf[t] += tmp;
        __syncthreads();
    }
    if (i < N) rowptr[i] = buf[t] - v;  // exclusive within block
    if (t == 255) bsum[blockIdx.x] = buf[255];
    if (t < NUM_GRAPHS && hist[t] > 0) atomicAdd(&pcnt[t], (float)hist[t]);
}

// ---- scan phase 2 (folded): block-offset + per-copy bases + dinv + xs + Wt -
__global__ __launch_bounds__(256) void k_scan3(int* __restrict__ rowptr,
                                               const int* __restrict__ bsum,
                                               const int* __restrict__ degc,
                                               int* __restrict__ base,
                                               float* __restrict__ dinv,
                                               const float* __restrict__ x,
                                               float* __restrict__ xs,
                                               const float* __restrict__ W2,
                                               const float* __restrict__ W3,
                                               unsigned short* __restrict__ Wt2,
                                               unsigned short* __restrict__ Wt3,
                                               int N) {
    __shared__ int red[256];
    int t = threadIdx.x;
    int b = blockIdx.x;
    red[t] = (t < b) ? bsum[t] : 0;  // b <= 195 < 256
    __syncthreads();
#pragma unroll
    for (int off = 128; off > 0; off >>= 1) {
        if (t < off) red[t] += red[t + off];
        __syncthreads();
    }
    int boff = red[0];
    int i = b * 256 + t;
    if (i < N) {
        int rp = rowptr[i] + boff;
        rowptr[i] = rp;
        int run = rp, tot = 0;
#pragma unroll
        for (int c = 0; c < 8; ++c) {
            int d = degc[c * N_NODES + i];
            base[c * N_NODES + i] = run;
            run += d;
            tot += d;
        }
        float dv = rsqrtf((float)tot + 1.0f);  // +1 = self loop
        dinv[i] = dv;
        xs[i * 3 + 0] = dv * x[i * 3 + 0];
        xs[i * 3 + 1] = dv * x[i * 3 + 1];
        xs[i * 3 + 2] = dv * x[i * 3 + 2];
    }
    if (i == 0) rowptr[N] = N_EDGES;
    // folded weight cast+transpose
    if (i < 64 * 128) {                       // Wt2: [f=128][k=64]
        int f = i / 64, k = i % 64;
        Wt2[i] = bf16_rne(W2[k * 128 + f]);
    } else if (i < 64 * 128 + 128 * 256) {    // Wt3: [f=256][k=128]
        int j = i - 64 * 128;
        int f = j / 128, k = j % 128;
        Wt3[j] = bf16_rne(W3[k * 256 + f]);
    }
}

// ---- CSR fill: no atomic; slot = base[copy][dst] + rank-within-copy --------
__global__ void k_fill(const int* __restrict__ row, const int* __restrict__ col,
                       const int* __restrict__ base, const int* __restrict__ pos,
                       int* __restrict__ csr_src, int E) {
    int e = blockIdx.x * blockDim.x + threadIdx.x;
    if (e >= E) return;
    int c8 = (e >> 8) & 7;
    csr_src[base[c8 * N_NODES + col[e]] + pos[e]] = row[e];
}

// ---- fused layer 1: p1 = dv*(xs[v]+Σxs[r]); h1' = dv*relu(p1 W1 + b1) ------
__global__ void k_layer1(const float* __restrict__ xs, const float* __restrict__ dinv,
                         const int* __restrict__ rowptr, const int* __restrict__ csr_src,
                         const float* __restrict__ W1, const float* __restrict__ b1,
                         unsigned short* __restrict__ out, int N) {
    int v = blockIdx.x * blockDim.x + threadIdx.x;
    if (v >= N) return;
    float a0 = xs[v * 3 + 0];
    float a1 = xs[v * 3 + 1];
    float a2 = xs[v * 3 + 2];
    int j = rowptr[v];
    int j1 = rowptr[v + 1];
    for (; j + 4 <= j1; j += 4) {
        int r0 = csr_src[j + 0], r1 = csr_src[j + 1];
        int r2 = csr_src[j + 2], r3 = csr_src[j + 3];
        float x00 = xs[r0 * 3 + 0], x01 = xs[r0 * 3 + 1], x02 = xs[r0 * 3 + 2];
        float x10 = xs[r1 * 3 + 0], x11 = xs[r1 * 3 + 1], x12 = xs[r1 * 3 + 2];
        float x20 = xs[r2 * 3 + 0], x21 = xs[r2 * 3 + 1], x22 = xs[r2 * 3 + 2];
        float x30 = xs[r3 * 3 + 0], x31 = xs[r3 * 3 + 1], x32 = xs[r3 * 3 + 2];
        a0 += x00; a1 += x01; a2 += x02;
        a0 += x10; a1 += x11; a2 += x12;
        a0 += x20; a1 += x21; a2 += x22;
        a0 += x30; a1 += x31; a2 += x32;
    }
    for (; j < j1; ++j) {
        int r = csr_src[j];
        a0 += xs[r * 3 + 0];
        a1 += xs[r * 3 + 1];
        a2 += xs[r * 3 + 2];
    }
    float dv = dinv[v];
    float p0 = dv * a0, p1 = dv * a1, p2 = dv * a2;
    unsigned short* ov = out + (long)v * 64;
#pragma unroll
    for (int f = 0; f < 64; f += 2) {
        float s0 = fmaf(p0, W1[f],     fmaf(p1, W1[64 + f],     fmaf(p2, W1[128 + f],     b1[f])));
        float s1 = fmaf(p0, W1[f + 1], fmaf(p1, W1[64 + f + 1], fmaf(p2, W1[128 + f + 1], b1[f + 1])));
        s0 = fmaxf(s0, 0.0f) * dv;  // pre-scale for next prop
        s1 = fmaxf(s1, 0.0f) * dv;
        unsigned pk = (unsigned)bf16_rne(s0) | ((unsigned)bf16_rne(s1) << 16);
        *(unsigned*)(ov + f) = pk;
    }
}

// ---- FUSED prop + MFMA GEMM per 16-row m-tile; optional fused mean-pool ----
// Gather = R15 2-row interleaved structure (established floor). Phase 2 =
// verified R9/R11 MFMA layout. POOL=true: h3 is consumed ONLY by the pool, so
// instead of writing 25 MB of H3 and re-reading it, accumulate relu(acc+bias)
// into per-block LDS partials (<=2 graph segments per 16-node block since
// graphs ~3125 nodes; 3rd-segment fallback = direct global atomic) and flush
// once to psum. Kills 50 MB of traffic + one launch.
template <int K, int F, bool PRESCALE, bool POOL>
__global__ __launch_bounds__(256) void k_fused(
        const unsigned short* __restrict__ h, const float* __restrict__ dinv,
        const int* __restrict__ rowptr, const int* __restrict__ csr_src,
        const unsigned short* __restrict__ Wt, const float* __restrict__ b,
        unsigned short* __restrict__ out, const int* __restrict__ batch,
        float* __restrict__ psum, int N) {
    constexpr int NF = F / 16;    // f-tiles: 8 (F=128) / 16 (F=256)
    constexpr int FPW = NF / 4;   // f-tiles per wave: 2 / 4
    constexpr int KB = K / 32;    // k-blocks: 2 / 4
    constexpr int KL = K / 64;    // features per lane in prop: 1 / 2
    constexpr int PADK = K + 8;
    __shared__ unsigned short plds[16][PADK];
    __shared__ float lps[2][256];  // pool partials (POOL only)
    __shared__ int gb[16];         // batch ids of block's rows (POOL only)
    int wave = threadIdx.x >> 6;
    int lane = threadIdx.x & 63;
    int t = threadIdx.x;
    int m0 = blockIdx.x * 16;

    if (POOL) {
        if (t < 16) gb[t] = batch[m0 + t];
        lps[0][t] = 0.0f;
        lps[1][t] = 0.0f;
    }

    // ---- phase 1: propagation into LDS, rows processed in pairs ----
    for (int pr = 0; pr < 2; ++pr) {
        int va = m0 + wave * 4 + pr * 2;
        int vb = va + 1;
        float acca[KL], accb[KL];
        const unsigned short* hva = h + (long)va * K + lane * KL;
        const unsigned short* hvb = h + (long)vb * K + lane * KL;
        if (KL == 2) {
            unsigned ua = *(const unsigned*)hva;
            unsigned ub = *(const unsigned*)hvb;
            acca[0] = __uint_as_float(ua << 16);
            acca[1] = __uint_as_float(ua & 0xFFFF0000u);
            accb[0] = __uint_as_float(ub << 16);
            accb[1] = __uint_as_float(ub & 0xFFFF0000u);
        } else {
            acca[0] = bfl(hva[0]);
            accb[0] = bfl(hvb[0]);
        }
        int ja  = __builtin_amdgcn_readfirstlane(rowptr[va]);
        int j1a = __builtin_amdgcn_readfirstlane(rowptr[va + 1]);
        int jb  = j1a;
        int j1b = __builtin_amdgcn_readfirstlane(rowptr[vb + 1]);
        while (ja + 8 <= j1a && jb + 8 <= j1b) {
            int ra[8], rb[8];
#pragma unroll
            for (int u = 0; u < 8; ++u) ra[u] = csr_src[ja + u];
#pragma unroll
            for (int u = 0; u < 8; ++u) rb[u] = csr_src[jb + u];
            if (KL == 2) {
                unsigned ta[8], tb[8];
#pragma unroll
                for (int u = 0; u < 8; ++u)
                    ta[u] = *(const unsigned*)(h + (long)ra[u] * K + lane * 2);
#pragma unroll
                for (int u = 0; u < 8; ++u)
                    tb[u] = *(const unsigned*)(h + (long)rb[u] * K + lane * 2);
#pragma unroll
                for (int u = 0; u < 8; ++u) {
                    acca[0] += __uint_as_float(ta[u] << 16);
                    acca[1] += __uint_as_float(ta[u] & 0xFFFF0000u);
                }
#pragma unroll
                for (int u = 0; u < 8; ++u) {
                    accb[0] += __uint_as_float(tb[u] << 16);
                    accb[1] += __uint_as_float(tb[u] & 0xFFFF0000u);
                }
            } else {
                unsigned short ta[8], tb[8];
#pragma unroll
                for (int u = 0; u < 8; ++u) ta[u] = h[(long)ra[u] * K + lane];
#pragma unroll
                for (int u = 0; u < 8; ++u) tb[u] = h[(long)rb[u] * K + lane];
#pragma unroll
                for (int u = 0; u < 8; ++u) acca[0] += bfl(ta[u]);
#pragma unroll
                for (int u = 0; u < 8; ++u) accb[0] += bfl(tb[u]);
            }
            ja += 8;
            jb += 8;
        }
        for (; ja + 8 <= j1a; ja += 8) {
            int r[8];
#pragma unroll
            for (int u = 0; u < 8; ++u) r[u] = csr_src[ja + u];
            if (KL == 2) {
                unsigned tv[8];
#pragma unroll
                for (int u = 0; u < 8; ++u)
                    tv[u] = *(const unsigned*)(h + (long)r[u] * K + lane * 2);
#pragma unroll
                for (int u = 0; u < 8; ++u) {
                    acca[0] += __uint_as_float(tv[u] << 16);
                    acca[1] += __uint_as_float(tv[u] & 0xFFFF0000u);
                }
            } else {
                unsigned short tv[8];
#pragma unroll
                for (int u = 0; u < 8; ++u) tv[u] = h[(long)r[u] * K + lane];
#pragma unroll
                for (int u = 0; u < 8; ++u) acca[0] += bfl(tv[u]);
            }
        }
        for (; ja < j1a; ++ja) {
            int r = csr_src[ja];
            if (KL == 2) {
                unsigned u = *(const unsigned*)(h + (long)r * K + lane * 2);
                acca[0] += __uint_as_float(u << 16);
                acca[1] += __uint_as_float(u & 0xFFFF0000u);
            } else {
                acca[0] += bfl(h[(long)r * K + lane]);
            }
        }
        for (; jb + 8 <= j1b; jb += 8) {
            int r[8];
#pragma unroll
            for (int u = 0; u < 8; ++u) r[u] = csr_src[jb + u];
            if (KL == 2) {
                unsigned tv[8];
#pragma unroll
                for (int u = 0; u < 8; ++u)
                    tv[u] = *(const unsigned*)(h + (long)r[u] * K + lane * 2);
#pragma unroll
                for (int u = 0; u < 8; ++u) {
                    accb[0] += __uint_as_float(tv[u] << 16);
                    accb[1] += __uint_as_float(tv[u] & 0xFFFF0000u);
                }
            } else {
                unsigned short tv[8];
#pragma unroll
                for (int u = 0; u < 8; ++u) tv[u] = h[(long)r[u] * K + lane];
#pragma unroll
                for (int u = 0; u < 8; ++u) accb[0] += bfl(tv[u]);
            }
        }
        for (; jb < j1b; ++jb) {
            int r = csr_src[jb];
            if (KL == 2) {
                unsigned u = *(const unsigned*)(h + (long)r * K + lane * 2);
                accb[0] += __uint_as_float(u << 16);
                accb[1] += __uint_as_float(u & 0xFFFF0000u);
            } else {
                accb[0] += bfl(h[(long)r * K + lane]);
            }
        }
        float da = dinv[va];
        float db = dinv[vb];
        int rla = wave * 4 + pr * 2;
        if (KL == 2) {
            unsigned pa = (unsigned)bf16_rne(da * acca[0]) | ((unsigned)bf16_rne(da * acca[1]) << 16);
            unsigned pb = (unsigned)bf16_rne(db * accb[0]) | ((unsigned)bf16_rne(db * accb[1]) << 16);
            *(unsigned*)&plds[rla][lane * 2] = pa;
            *(unsigned*)&plds[rla + 1][lane * 2] = pb;
        } else {
            plds[rla][lane] = bf16_rne(da * acca[0]);
            plds[rla + 1][lane] = bf16_rne(db * accb[0]);
        }
    }
    __syncthreads();

    // ---- phase 2: MFMA (layout verified R9/R11) ----
    int quad = lane >> 4;
    int l16 = lane & 15;
    bf16x8 afr[KB];
#pragma unroll
    for (int kb = 0; kb < KB; ++kb)
        afr[kb] = *(const bf16x8*)(const void*)&plds[l16][kb * 32 + quad * 8];
#pragma unroll
    for (int fi = 0; fi < FPW; ++fi) {
        int f0 = (wave * FPW + fi) * 16;
        const unsigned short* wrow = Wt + (long)(f0 + l16) * K + quad * 8;
        f32x4 acc4 = {0.f, 0.f, 0.f, 0.f};
#pragma unroll
        for (int kb = 0; kb < KB; ++kb) {
            bf16x8 bb = *(const bf16x8*)(const void*)(wrow + kb * 32);
            acc4 = __builtin_amdgcn_mfma_f32_16x16x32_bf16(afr[kb], bb, acc4, 0, 0, 0);
        }
        float bias = b[f0 + l16];
#pragma unroll
        for (int r = 0; r < 4; ++r) {
            int rowloc = quad * 4 + r;
            float val = fmaxf(acc4[r] + bias, 0.0f);
            if (POOL) {
                int g = gb[rowloc];
                int g0 = gb[0], g15 = gb[15];
                if (g == g0) {
                    atomicAdd(&lps[0][f0 + l16], val);
                } else if (g == g15) {
                    atomicAdd(&lps[1][f0 + l16], val);
                } else {  // >2 segments: impossible for ~3125-node graphs
                    atomicAdd(&psum[g * 256 + f0 + l16], val);
                }
            } else {
                int m = m0 + rowloc;
                if (PRESCALE) val *= dinv[m];
                out[(long)m * F + f0 + l16] = bf16_rne(val);
            }
        }
    }
    if (POOL) {
        __syncthreads();
        int g0 = gb[0], g15 = gb[15];
        atomicAdd(&psum[g0 * 256 + t], lps[0][t]);
        if (g15 != g0) atomicAdd(&psum[g15 * 256 + t], lps[1][t]);
    }
}

// ---- final FC --------------------------------------------------------------
__global__ void k_fc(const float* __restrict__ psum, const float* __restrict__ pcnt,
                     const float* __restrict__ Wfc, const float* __restrict__ bfc,
                     float* __restrict__ out) {
    int tid = blockIdx.x * blockDim.x + threadIdx.x;
    if (tid >= NUM_GRAPHS * NUM_CLASSES) return;
    int g = tid / NUM_CLASSES;
    int c = tid % NUM_CLASSES;
    float s = 0.0f;
#pragma unroll 8
    for (int k = 0; k < 256; ++k) s = fmaf(psum[g * 256 + k], Wfc[k * NUM_CLASSES + c], s);
    float cnt = pcnt[g];
    cnt = cnt > 1.0f ? cnt : 1.0f;
    out[tid] = s / cnt + bfc[c];
}

extern "C" void kernel_launch(void* const* d_in, const int* in_sizes, int n_in,
                              void* d_out, int out_size, void* d_ws, size_t ws_size,
                              hipStream_t stream) {
    const float* x     = (const float*)d_in[0];
    const int*   ei    = (const int*)d_in[1];
    const int*   batch = (const int*)d_in[2];
    const float* W1    = (const float*)d_in[3];
    const float* b1    = (const float*)d_in[4];
    const float* W2    = (const float*)d_in[5];
    const float* b2    = (const float*)d_in[6];
    const float* W3    = (const float*)d_in[7];
    const float* b3    = (const float*)d_in[8];
    const float* Wfc   = (const float*)d_in[9];
    const float* bfc   = (const float*)d_in[10];
    float* out = (float*)d_out;

    const int* row = ei;            // src
    const int* col = ei + N_EDGES;  // dst

    // workspace layout (H3 eliminated), bf16 arrays 16B-aligned
    float*  xs   = (float*)d_ws;                         // N*3 f32 (pre-scaled x)
    float*  dinv = xs + (size_t)N_NODES * 3;             // N
    float*  psum = dinv + N_NODES;                       // 16*256
    float*  pcnt = psum + NUM_GRAPHS * 256;              // 16
    unsigned short* X   = (unsigned short*)(pcnt + NUM_GRAPHS);  // N*128 bf16 (h1')
    unsigned short* Y   = X + (size_t)N_NODES * 128;             // N*128 bf16 (h2')
    unsigned short* Wt2 = Y + (size_t)N_NODES * 128;             // 128*64
    unsigned short* Wt3 = Wt2 + 128 * 64;                        // 256*128
    int* degc   = (int*)(Wt3 + 256 * 128);               // 8*N (XCD-local copies)
    int* base   = degc + 8 * N_NODES;                    // 8*N (per-copy slot bases)
    int* rowptr = base + 8 * N_NODES;                    // N+1
    int* csrsrc = rowptr + N_NODES + 1;                  // E
    int* pos    = csrsrc + N_EDGES;                      // E
    int* bsum   = pos + N_EDGES;                         // SCAN_BLOCKS

    hipMemsetAsync(degc, 0, 8 * N_NODES * sizeof(int), stream);
    hipMemsetAsync(psum, 0, (NUM_GRAPHS * 256 + NUM_GRAPHS) * sizeof(float), stream);

    // ---- CSR build + norms + pre-scaled x + weight casts ----
    k_deg<<<nblk(N_EDGES), 256, 0, stream>>>(col, degc, pos, N_EDGES);
    k_scan1<<<SCAN_BLOCKS, 256, 0, stream>>>(degc, rowptr, bsum, batch, pcnt, N_NODES);
    k_scan3<<<SCAN_BLOCKS, 256, 0, stream>>>(rowptr, bsum, degc, base, dinv, x, xs,
                                             W2, W3, Wt2, Wt3, N_NODES);
    k_fill<<<nblk(N_EDGES), 256, 0, stream>>>(row, col, base, pos, csrsrc, N_EDGES);

    // ---- layer 1 (fused prop+linear): X = h1' = d*relu((A~x)W1+b1), bf16 ---
    k_layer1<<<nblk(N_NODES), 256, 0, stream>>>(xs, dinv, rowptr, csrsrc, W1, b1, X, N_NODES);

    int mtiles = N_NODES / 16;  // 3125, exact

    // ---- layer 2 fused: Y = h2' = d*relu((A~-apply X) W2 + b2) -------------
    k_fused<64, 128, true, false><<<mtiles, 256, 0, stream>>>(
        X, dinv, rowptr, csrsrc, Wt2, b2, Y, batch, psum, N_NODES);

    // ---- layer 3 fused + POOL: psum += relu((A~-apply Y) W3 + b3) ----------
    k_fused<128, 256, false, true><<<mtiles, 256, 0, stream>>>(
        Y, dinv, rowptr, csrsrc, Wt3, b3, (unsigned short*)nullptr, batch, psum, N_NODES);

    // ---- FC ----
    k_fc<<<nblk(NUM_GRAPHS * NUM_CLASSES), 256, 0, stream>>>(psum, pcnt, Wfc, bfc, out);
}

// Round 18
// 253.901 us; speedup vs baseline: 1.1358x; 1.1358x over previous
//
#include <hip/hip_runtime.h>

#define N_NODES 50000
#define N_EDGES 800000
#define NUM_GRAPHS 16
#define NUM_CLASSES 247
#define SCAN_BLOCKS ((N_NODES + 255) / 256)  // 196

typedef __attribute__((ext_vector_type(8))) short bf16x8;
typedef __attribute__((ext_vector_type(4))) float f32x4;

static inline int nblk(long n) { return (int)((n + 255) / 256); }

__device__ __forceinline__ float bfl(unsigned short u) {
    return __uint_as_float((unsigned)u << 16);
}
__device__ __forceinline__ unsigned short bf16_rne(float f) {
    unsigned u = __float_as_uint(f);
    u += 0x7FFF + ((u >> 16) & 1);
    return (unsigned short)(u >> 16);
}

// ---- degree histogram into 8 XCD-local copies; returns rank within copy ----
__global__ void k_deg(const int* __restrict__ col, int* __restrict__ degc,
                      int* __restrict__ pos, int E) {
    int e = blockIdx.x * blockDim.x + threadIdx.x;
    if (e >= E) return;
    int c8 = (e >> 8) & 7;
    pos[e] = atomicAdd(&degc[c8 * N_NODES + col[e]], 1);
}

// ---- scan phase 1: per-block exclusive scan of total degree + batch hist ---
__global__ __launch_bounds__(256) void k_scan1(const int* __restrict__ degc,
                                               int* __restrict__ rowptr,
                                               int* __restrict__ bsum,
                                               const int* __restrict__ batch,
                                               float* __restrict__ pcnt, int N) {
    __shared__ int buf[256];
    __shared__ int hist[NUM_GRAPHS];
    int t = threadIdx.x;
    if (t < NUM_GRAPHS) hist[t] = 0;
    int i = blockIdx.x * 256 + t;
    int v = 0;
    if (i < N) {
#pragma unroll
        for (int c = 0; c < 8; ++c) v += degc[c * N_NODES + i];
        atomicAdd(&hist[batch[i]], 1);
    }
    buf[t] = v;
    __syncthreads();
#pragma unroll
    for (int off = 1; off < 256; off <<= 1) {
        int tmp = (t >= off) ? buf[t - off] : 0;
        __syncthreads();
        if (t >= off) buf[t] += tmp;
        __syncthreads();
    }
    if (i < N) rowptr[i] = buf[t] - v;  // exclusive within block
    if (t == 255) bsum[blockIdx.x] = buf[255];
    if (t < NUM_GRAPHS && hist[t] > 0) atomicAdd(&pcnt[t], (float)hist[t]);
}

// ---- scan phase 2 (folded): block-offset + per-copy bases + dinv + xs + Wt -
__global__ __launch_bounds__(256) void k_scan3(int* __restrict__ rowptr,
                                               const int* __restrict__ bsum,
                                               const int* __restrict__ degc,
                                               int* __restrict__ base,
                                               float* __restrict__ dinv,
                                               const float* __restrict__ x,
                                               float* __restrict__ xs,
                                               const float* __restrict__ W2,
                                               const float* __restrict__ W3,
                                               unsigned short* __restrict__ Wt2,
                                               unsigned short* __restrict__ Wt3,
                                               int N) {
    __shared__ int red[256];
    int t = threadIdx.x;
    int b = blockIdx.x;
    red[t] = (t < b) ? bsum[t] : 0;  // b <= 195 < 256
    __syncthreads();
#pragma unroll
    for (int off = 128; off > 0; off >>= 1) {
        if (t < off) red[t] += red[t + off];
        __syncthreads();
    }
    int boff = red[0];
    int i = b * 256 + t;
    if (i < N) {
        int rp = rowptr[i] + boff;
        rowptr[i] = rp;
        int run = rp, tot = 0;
#pragma unroll
        for (int c = 0; c < 8; ++c) {
            int d = degc[c * N_NODES + i];
            base[c * N_NODES + i] = run;
            run += d;
            tot += d;
        }
        float dv = rsqrtf((float)tot + 1.0f);  // +1 = self loop
        dinv[i] = dv;
        xs[i * 3 + 0] = dv * x[i * 3 + 0];
        xs[i * 3 + 1] = dv * x[i * 3 + 1];
        xs[i * 3 + 2] = dv * x[i * 3 + 2];
    }
    if (i == 0) rowptr[N] = N_EDGES;
    // folded weight cast+transpose
    if (i < 64 * 128) {                       // Wt2: [f=128][k=64]
        int f = i / 64, k = i % 64;
        Wt2[i] = bf16_rne(W2[k * 128 + f]);
    } else if (i < 64 * 128 + 128 * 256) {    // Wt3: [f=256][k=128]
        int j = i - 64 * 128;
        int f = j / 128, k = j % 128;
        Wt3[j] = bf16_rne(W3[k * 256 + f]);
    }
}

// ---- CSR fill: no atomic; slot = base[copy][dst] + rank-within-copy --------
__global__ void k_fill(const int* __restrict__ row, const int* __restrict__ col,
                       const int* __restrict__ base, const int* __restrict__ pos,
                       int* __restrict__ csr_src, int E) {
    int e = blockIdx.x * blockDim.x + threadIdx.x;
    if (e >= E) return;
    int c8 = (e >> 8) & 7;
    csr_src[base[c8 * N_NODES + col[e]] + pos[e]] = row[e];
}

// ---- fused layer 1: p1 = dv*(xs[v]+Σxs[r]); h1' = dv*relu(p1 W1 + b1) ------
__global__ void k_layer1(const float* __restrict__ xs, const float* __restrict__ dinv,
                         const int* __restrict__ rowptr, const int* __restrict__ csr_src,
                         const float* __restrict__ W1, const float* __restrict__ b1,
                         unsigned short* __restrict__ out, int N) {
    int v = blockIdx.x * blockDim.x + threadIdx.x;
    if (v >= N) return;
    float a0 = xs[v * 3 + 0];
    float a1 = xs[v * 3 + 1];
    float a2 = xs[v * 3 + 2];
    int j = rowptr[v];
    int j1 = rowptr[v + 1];
    for (; j + 4 <= j1; j += 4) {
        int r0 = csr_src[j + 0], r1 = csr_src[j + 1];
        int r2 = csr_src[j + 2], r3 = csr_src[j + 3];
        float x00 = xs[r0 * 3 + 0], x01 = xs[r0 * 3 + 1], x02 = xs[r0 * 3 + 2];
        float x10 = xs[r1 * 3 + 0], x11 = xs[r1 * 3 + 1], x12 = xs[r1 * 3 + 2];
        float x20 = xs[r2 * 3 + 0], x21 = xs[r2 * 3 + 1], x22 = xs[r2 * 3 + 2];
        float x30 = xs[r3 * 3 + 0], x31 = xs[r3 * 3 + 1], x32 = xs[r3 * 3 + 2];
        a0 += x00; a1 += x01; a2 += x02;
        a0 += x10; a1 += x11; a2 += x12;
        a0 += x20; a1 += x21; a2 += x22;
        a0 += x30; a1 += x31; a2 += x32;
    }
    for (; j < j1; ++j) {
        int r = csr_src[j];
        a0 += xs[r * 3 + 0];
        a1 += xs[r * 3 + 1];
        a2 += xs[r * 3 + 2];
    }
    float dv = dinv[v];
    float p0 = dv * a0, p1 = dv * a1, p2 = dv * a2;
    unsigned short* ov = out + (long)v * 64;
#pragma unroll
    for (int f = 0; f < 64; f += 2) {
        float s0 = fmaf(p0, W1[f],     fmaf(p1, W1[64 + f],     fmaf(p2, W1[128 + f],     b1[f])));
        float s1 = fmaf(p0, W1[f + 1], fmaf(p1, W1[64 + f + 1], fmaf(p2, W1[128 + f + 1], b1[f + 1])));
        s0 = fmaxf(s0, 0.0f) * dv;  // pre-scale for next prop
        s1 = fmaxf(s1, 0.0f) * dv;
        unsigned pk = (unsigned)bf16_rne(s0) | ((unsigned)bf16_rne(s1) << 16);
        *(unsigned*)(ov + f) = pk;
    }
}

// ---- FUSED prop + MFMA GEMM per 16-row m-tile; optional fused mean-pool ----
// Gather = R15 2-row interleaved structure. Phase 2 = verified R9/R11 MFMA.
// POOL epilogue (R18, feather-weight): per lane the 4 C/D rows share feature
// f0+l16, so s = Σ_r relu(acc4[r]+bias) is register-only; two shfl_xor fold
// the 4 quads; quad 0 issues ONE global atomic per feature. No LDS arrays, no
// LDS atomics, no trailing sync — keeps regalloc identical to the non-pool
// variant (R17 lesson: heavy epilogue dropped VGPR 40->28 and collapsed
// gather MLP). Mixed-graph blocks (~15/3125) take a per-element slow path.
template <int K, int F, bool PRESCALE, bool POOL>
__global__ __launch_bounds__(256) void k_fused(
        const unsigned short* __restrict__ h, const float* __restrict__ dinv,
        const int* __restrict__ rowptr, const int* __restrict__ csr_src,
        const unsigned short* __restrict__ Wt, const float* __restrict__ b,
        unsigned short* __restrict__ out, const int* __restrict__ batch,
        float* __restrict__ psum, int N) {
    constexpr int NF = F / 16;    // f-tiles: 8 (F=128) / 16 (F=256)
    constexpr int FPW = NF / 4;   // f-tiles per wave: 2 / 4
    constexpr int KB = K / 32;    // k-blocks: 2 / 4
    constexpr int KL = K / 64;    // features per lane in prop: 1 / 2
    constexpr int PADK = K + 8;
    __shared__ unsigned short plds[16][PADK];
    int wave = threadIdx.x >> 6;
    int lane = threadIdx.x & 63;
    int m0 = blockIdx.x * 16;

    // ---- phase 1: propagation into LDS, rows processed in pairs ----
    for (int pr = 0; pr < 2; ++pr) {
        int va = m0 + wave * 4 + pr * 2;
        int vb = va + 1;
        float acca[KL], accb[KL];
        const unsigned short* hva = h + (long)va * K + lane * KL;
        const unsigned short* hvb = h + (long)vb * K + lane * KL;
        if (KL == 2) {
            unsigned ua = *(const unsigned*)hva;
            unsigned ub = *(const unsigned*)hvb;
            acca[0] = __uint_as_float(ua << 16);
            acca[1] = __uint_as_float(ua & 0xFFFF0000u);
            accb[0] = __uint_as_float(ub << 16);
            accb[1] = __uint_as_float(ub & 0xFFFF0000u);
        } else {
            acca[0] = bfl(hva[0]);
            accb[0] = bfl(hvb[0]);
        }
        int ja  = __builtin_amdgcn_readfirstlane(rowptr[va]);
        int j1a = __builtin_amdgcn_readfirstlane(rowptr[va + 1]);
        int jb  = j1a;
        int j1b = __builtin_amdgcn_readfirstlane(rowptr[vb + 1]);
        while (ja + 8 <= j1a && jb + 8 <= j1b) {
            int ra[8], rb[8];
#pragma unroll
            for (int u = 0; u < 8; ++u) ra[u] = csr_src[ja + u];
#pragma unroll
            for (int u = 0; u < 8; ++u) rb[u] = csr_src[jb + u];
            if (KL == 2) {
                unsigned ta[8], tb[8];
#pragma unroll
                for (int u = 0; u < 8; ++u)
                    ta[u] = *(const unsigned*)(h + (long)ra[u] * K + lane * 2);
#pragma unroll
                for (int u = 0; u < 8; ++u)
                    tb[u] = *(const unsigned*)(h + (long)rb[u] * K + lane * 2);
#pragma unroll
                for (int u = 0; u < 8; ++u) {
                    acca[0] += __uint_as_float(ta[u] << 16);
                    acca[1] += __uint_as_float(ta[u] & 0xFFFF0000u);
                }
#pragma unroll
                for (int u = 0; u < 8; ++u) {
                    accb[0] += __uint_as_float(tb[u] << 16);
                    accb[1] += __uint_as_float(tb[u] & 0xFFFF0000u);
                }
            } else {
                unsigned short ta[8], tb[8];
#pragma unroll
                for (int u = 0; u < 8; ++u) ta[u] = h[(long)ra[u] * K + lane];
#pragma unroll
                for (int u = 0; u < 8; ++u) tb[u] = h[(long)rb[u] * K + lane];
#pragma unroll
                for (int u = 0; u < 8; ++u) acca[0] += bfl(ta[u]);
#pragma unroll
                for (int u = 0; u < 8; ++u) accb[0] += bfl(tb[u]);
            }
            ja += 8;
            jb += 8;
        }
        for (; ja + 8 <= j1a; ja += 8) {
            int r[8];
#pragma unroll
            for (int u = 0; u < 8; ++u) r[u] = csr_src[ja + u];
            if (KL == 2) {
                unsigned tv[8];
#pragma unroll
                for (int u = 0; u < 8; ++u)
                    tv[u] = *(const unsigned*)(h + (long)r[u] * K + lane * 2);
#pragma unroll
                for (int u = 0; u < 8; ++u) {
                    acca[0] += __uint_as_float(tv[u] << 16);
                    acca[1] += __uint_as_float(tv[u] & 0xFFFF0000u);
                }
            } else {
                unsigned short tv[8];
#pragma unroll
                for (int u = 0; u < 8; ++u) tv[u] = h[(long)r[u] * K + lane];
#pragma unroll
                for (int u = 0; u < 8; ++u) acca[0] += bfl(tv[u]);
            }
        }
        for (; ja < j1a; ++ja) {
            int r = csr_src[ja];
            if (KL == 2) {
                unsigned u = *(const unsigned*)(h + (long)r * K + lane * 2);
                acca[0] += __uint_as_float(u << 16);
                acca[1] += __uint_as_float(u & 0xFFFF0000u);
            } else {
                acca[0] += bfl(h[(long)r * K + lane]);
            }
        }
        for (; jb + 8 <= j1b; jb += 8) {
            int r[8];
#pragma unroll
            for (int u = 0; u < 8; ++u) r[u] = csr_src[jb + u];
            if (KL == 2) {
                unsigned tv[8];
#pragma unroll
                for (int u = 0; u < 8; ++u)
                    tv[u] = *(const unsigned*)(h + (long)r[u] * K + lane * 2);
#pragma unroll
                for (int u = 0; u < 8; ++u) {
                    accb[0] += __uint_as_float(tv[u] << 16);
                    accb[1] += __uint_as_float(tv[u] & 0xFFFF0000u);
                }
            } else {
                unsigned short tv[8];
#pragma unroll
                for (int u = 0; u < 8; ++u) tv[u] = h[(long)r[u] * K + lane];
#pragma unroll
                for (int u = 0; u < 8; ++u) accb[0] += bfl(tv[u]);
            }
        }
        for (; jb < j1b; ++jb) {
            int r = csr_src[jb];
            if (KL == 2) {
                unsigned u = *(const unsigned*)(h + (long)r * K + lane * 2);
                accb[0] += __uint_as_float(u << 16);
                accb[1] += __uint_as_float(u & 0xFFFF0000u);
            } else {
                accb[0] += bfl(h[(long)r * K + lane]);
            }
        }
        float da = dinv[va];
        float db = dinv[vb];
        int rla = wave * 4 + pr * 2;
        if (KL == 2) {
            unsigned pa = (unsigned)bf16_rne(da * acca[0]) | ((unsigned)bf16_rne(da * acca[1]) << 16);
            unsigned pb = (unsigned)bf16_rne(db * accb[0]) | ((unsigned)bf16_rne(db * accb[1]) << 16);
            *(unsigned*)&plds[rla][lane * 2] = pa;
            *(unsigned*)&plds[rla + 1][lane * 2] = pb;
        } else {
            plds[rla][lane] = bf16_rne(da * acca[0]);
            plds[rla + 1][lane] = bf16_rne(db * accb[0]);
        }
    }
    __syncthreads();

    // ---- phase 2: MFMA (layout verified R9/R11) ----
    int quad = lane >> 4;
    int l16 = lane & 15;
    bf16x8 afr[KB];
#pragma unroll
    for (int kb = 0; kb < KB; ++kb)
        afr[kb] = *(const bf16x8*)(const void*)&plds[l16][kb * 32 + quad * 8];
#pragma unroll
    for (int fi = 0; fi < FPW; ++fi) {
        int f0 = (wave * FPW + fi) * 16;
        const unsigned short* wrow = Wt + (long)(f0 + l16) * K + quad * 8;
        f32x4 acc4 = {0.f, 0.f, 0.f, 0.f};
#pragma unroll
        for (int kb = 0; kb < KB; ++kb) {
            bf16x8 bb = *(const bf16x8*)(const void*)(wrow + kb * 32);
            acc4 = __builtin_amdgcn_mfma_f32_16x16x32_bf16(afr[kb], bb, acc4, 0, 0, 0);
        }
        float bias = b[f0 + l16];
        if (POOL) {
            int g0 = batch[m0];
            int g15 = batch[m0 + 15];
            if (g0 == g15) {  // uniform block (all but ~15 of 3125)
                float s = fmaxf(acc4[0] + bias, 0.0f);
                s += fmaxf(acc4[1] + bias, 0.0f);
                s += fmaxf(acc4[2] + bias, 0.0f);
                s += fmaxf(acc4[3] + bias, 0.0f);
                s += __shfl_xor(s, 16);
                s += __shfl_xor(s, 32);
                if (quad == 0) atomicAdd(&psum[g0 * 256 + f0 + l16], s);
            } else {  // graph boundary inside block: per-element atomics
#pragma unroll
                for (int r = 0; r < 4; ++r) {
                    int m = m0 + quad * 4 + r;
                    float val = fmaxf(acc4[r] + bias, 0.0f);
                    atomicAdd(&psum[batch[m] * 256 + f0 + l16], val);
                }
            }
        } else {
#pragma unroll
            for (int r = 0; r < 4; ++r) {
                int m = m0 + quad * 4 + r;
                float val = fmaxf(acc4[r] + bias, 0.0f);
                if (PRESCALE) val *= dinv[m];
                out[(long)m * F + f0 + l16] = bf16_rne(val);
            }
        }
    }
}

// ---- final FC --------------------------------------------------------------
__global__ void k_fc(const float* __restrict__ psum, const float* __restrict__ pcnt,
                     const float* __restrict__ Wfc, const float* __restrict__ bfc,
                     float* __restrict__ out) {
    int tid = blockIdx.x * blockDim.x + threadIdx.x;
    if (tid >= NUM_GRAPHS * NUM_CLASSES) return;
    int g = tid / NUM_CLASSES;
    int c = tid % NUM_CLASSES;
    float s = 0.0f;
#pragma unroll 8
    for (int k = 0; k < 256; ++k) s = fmaf(psum[g * 256 + k], Wfc[k * NUM_CLASSES + c], s);
    float cnt = pcnt[g];
    cnt = cnt > 1.0f ? cnt : 1.0f;
    out[tid] = s / cnt + bfc[c];
}

extern "C" void kernel_launch(void* const* d_in, const int* in_sizes, int n_in,
                              void* d_out, int out_size, void* d_ws, size_t ws_size,
                              hipStream_t stream) {
    const float* x     = (const float*)d_in[0];
    const int*   ei    = (const int*)d_in[1];
    const int*   batch = (const int*)d_in[2];
    const float* W1    = (const float*)d_in[3];
    const float* b1    = (const float*)d_in[4];
    const float* W2    = (const float*)d_in[5];
    const float* b2    = (const float*)d_in[6];
    const float* W3    = (const float*)d_in[7];
    const float* b3    = (const float*)d_in[8];
    const float* Wfc   = (const float*)d_in[9];
    const float* bfc   = (const float*)d_in[10];
    float* out = (float*)d_out;

    const int* row = ei;            // src
    const int* col = ei + N_EDGES;  // dst

    // workspace layout, bf16 arrays 16B-aligned
    float*  xs   = (float*)d_ws;                         // N*3 f32 (pre-scaled x)
    float*  dinv = xs + (size_t)N_NODES * 3;             // N
    float*  psum = dinv + N_NODES;                       // 16*256
    float*  pcnt = psum + NUM_GRAPHS * 256;              // 16
    unsigned short* X   = (unsigned short*)(pcnt + NUM_GRAPHS);  // N*128 bf16 (h1')
    unsigned short* Y   = X + (size_t)N_NODES * 128;             // N*128 bf16 (h2')
    unsigned short* Wt2 = Y + (size_t)N_NODES * 128;             // 128*64
    unsigned short* Wt3 = Wt2 + 128 * 64;                        // 256*128
    int* degc   = (int*)(Wt3 + 256 * 128);               // 8*N (XCD-local copies)
    int* base   = degc + 8 * N_NODES;                    // 8*N (per-copy slot bases)
    int* rowptr = base + 8 * N_NODES;                    // N+1
    int* csrsrc = rowptr + N_NODES + 1;                  // E
    int* pos    = csrsrc + N_EDGES;                      // E
    int* bsum   = pos + N_EDGES;                         // SCAN_BLOCKS

    hipMemsetAsync(degc, 0, 8 * N_NODES * sizeof(int), stream);
    hipMemsetAsync(psum, 0, (NUM_GRAPHS * 256 + NUM_GRAPHS) * sizeof(float), stream);

    // ---- CSR build + norms + pre-scaled x + weight casts ----
    k_deg<<<nblk(N_EDGES), 256, 0, stream>>>(col, degc, pos, N_EDGES);
    k_scan1<<<SCAN_BLOCKS, 256, 0, stream>>>(degc, rowptr, bsum, batch, pcnt, N_NODES);
    k_scan3<<<SCAN_BLOCKS, 256, 0, stream>>>(rowptr, bsum, degc, base, dinv, x, xs,
                                             W2, W3, Wt2, Wt3, N_NODES);
    k_fill<<<nblk(N_EDGES), 256, 0, stream>>>(row, col, base, pos, csrsrc, N_EDGES);

    // ---- layer 1 (fused prop+linear): X = h1' = d*relu((A~x)W1+b1), bf16 ---
    k_layer1<<<nblk(N_NODES), 256, 0, stream>>>(xs, dinv, rowptr, csrsrc, W1, b1, X, N_NODES);

    int mtiles = N_NODES / 16;  // 3125, exact

    // ---- layer 2 fused: Y = h2' = d*relu((A~-apply X) W2 + b2) -------------
    k_fused<64, 128, true, false><<<mtiles, 256, 0, stream>>>(
        X, dinv, rowptr, csrsrc, Wt2, b2, Y, batch, psum, N_NODES);

    // ---- layer 3 fused + POOL: psum += relu((A~-apply Y) W3 + b3) ----------
    k_fused<128, 256, false, true><<<mtiles, 256, 0, stream>>>(
        Y, dinv, rowptr, csrsrc, Wt3, b3, (unsigned short*)nullptr, batch, psum, N_NODES);

    // ---- FC ----
    k_fc<<<nblk(NUM_GRAPHS * NUM_CLASSES), 256, 0, stream>>>(psum, pcnt, Wfc, bfc, out);
}